// Round 14
// baseline (153.684 us; speedup 1.0000x reference)
//
#include <hip/hip_runtime.h>
#include <math.h>

typedef __bf16 bf16;
typedef __bf16 bf16x8 __attribute__((ext_vector_type(8)));
typedef __bf16 bf16x4 __attribute__((ext_vector_type(4)));
typedef __bf16 bf16x2 __attribute__((ext_vector_type(2)));
typedef float floatx4 __attribute__((ext_vector_type(4)));
typedef float floatx16 __attribute__((ext_vector_type(16)));
typedef unsigned int uintx4 __attribute__((ext_vector_type(4)));

#define T_SEQ 2048
#define NH 16
#define HD 64
#define HDIM 1024
#define BATCH 2
#define SCALE 0.03125f  // 1/sqrt(1024) per reference

static __device__ __forceinline__ floatx4 mfma16(bf16x8 a, bf16x8 b, floatx4 c) {
  return __builtin_amdgcn_mfma_f32_16x16x32_bf16(a, b, c, 0, 0, 0);
}
static __device__ __forceinline__ floatx16 mfma32(bf16x8 a, bf16x8 b, floatx16 c) {
  return __builtin_amdgcn_mfma_f32_32x32x16_bf16(a, b, c, 0, 0, 0);
}

static __device__ __forceinline__ unsigned int packbf(float a, float b) {
  bf16x2 t; t[0] = (bf16)a; t[1] = (bf16)b;
  return __builtin_bit_cast(unsigned int, t);
}

static __device__ __forceinline__ bf16x8 cvt_pack(floatx4 lo, floatx4 hi) {
  bf16x8 r;
  r[0] = (bf16)lo[0]; r[1] = (bf16)lo[1]; r[2] = (bf16)lo[2]; r[3] = (bf16)lo[3];
  r[4] = (bf16)hi[0]; r[5] = (bf16)hi[1]; r[6] = (bf16)hi[2]; r[7] = (bf16)hi[3];
  return r;
}

typedef const __attribute__((address_space(1))) void* gas_ptr;
typedef __attribute__((address_space(3))) void* las_ptr;
static __device__ __forceinline__ void load_lds16(const bf16* g, bf16* l) {
  __builtin_amdgcn_global_load_lds((gas_ptr)g, (las_ptr)l, 16, 0, 0);
}

// ---------------------------------------------------------------------------
// cvt: x (4M) and Wq/Wk/Wv (1M each) fp32 -> bf16.  grid (4096, 4) x 256.
// ---------------------------------------------------------------------------
__global__ __launch_bounds__(256) void cvt_f32_bf16(
    const float* __restrict__ x, const float* __restrict__ Wq,
    const float* __restrict__ Wk, const float* __restrict__ Wv,
    bf16* __restrict__ xb, bf16* __restrict__ wb) {
  const int seg = blockIdx.y;
  const float* src; bf16* dst; int n;
  if (seg == 0)      { src = x;  dst = xb;                 n = BATCH * T_SEQ * HDIM; }
  else if (seg == 1) { src = Wq; dst = wb;                 n = HDIM * HDIM; }
  else if (seg == 2) { src = Wk; dst = wb + HDIM * HDIM;   n = HDIM * HDIM; }
  else               { src = Wv; dst = wb + 2*HDIM*HDIM;   n = HDIM * HDIM; }
  const int i4 = (blockIdx.x * 256 + threadIdx.x) * 4;
  if (i4 < n) {
    floatx4 v = *(const floatx4*)(src + i4);
    bf16x4 o; o[0]=(bf16)v[0]; o[1]=(bf16)v[1]; o[2]=(bf16)v[2]; o[3]=(bf16)v[3];
    *(bf16x4*)(dst + i4) = o;
  }
}

// ---------------------------------------------------------------------------
// QKV GEMM v6: COUNTED-vmcnt 3-buffer pipeline (T3/T4-lite).
// __syncthreads()'s implicit vmcnt(0) drained the prefetch every window (the
// ~20-25% barrier-drain stall, guide Sec.5).  v6 keeps TWO windows in flight:
//   iter k: s_waitcnt vmcnt(4)   (own stage-k loads done; stage-k+1 flying)
//           s_barrier            (all waves' stage-k complete -> tile visible)
//           GSTAGE(k+2)          (buffer (k+2)%3 == (k-1)%3: its readers
//                                 finished their ds_reads before barrier k)
//           compute window k
// Last iter waits vmcnt(0).  3x16KB buffers = 48 KB LDS -> 3 blocks/CU.
// Packed K/V epilogue (LDS-staged vector stores) unchanged from v5.
// grid (32, 24) x 256.
// ---------------------------------------------------------------------------
__global__ __launch_bounds__(256) void qkv_gemm_lds(
    const bf16* __restrict__ xb, const bf16* __restrict__ wb,
    const float* __restrict__ bq, const float* __restrict__ bk,
    const float* __restrict__ bv, bf16* __restrict__ qkv) {
  __shared__ __align__(16) bf16 smem[24576];   // 48 KB: A bufs @ s*4096, B @ 12288+s*4096

  const int m0  = blockIdx.x * 128;
  const int n0g = blockIdx.y * 128;
  const int z   = n0g >> 10;
  const float* bias = (z == 0) ? bq : (z == 1) ? bk : bv;
  bf16* out = qkv + (size_t)z * BATCH * T_SEQ * HDIM;

  const int lane = threadIdx.x & 63;
  const int w    = threadIdx.x >> 6;
  const int l15  = lane & 15;
  const int quad = lane >> 4;
  const int wm = w & 1, wn = w >> 1;

  const int srow = w * 32 + (lane >> 2);
  const int scol = (lane & 3) * 8;
  const bf16* aG0 = xb + (size_t)(m0 + srow) * HDIM + scol;
  const bf16* aG1 = xb + (size_t)(m0 + srow + 16) * HDIM + scol;
  const bf16* bG0 = wb + (size_t)(n0g + srow) * HDIM + scol;
  const bf16* bG1 = wb + (size_t)(n0g + srow + 16) * HDIM + scol;

#define GSTAGE(S, KOFF)                                                      \
  {                                                                          \
    bf16* aB = smem + (S) * 4096;                                            \
    bf16* bB = smem + 12288 + (S) * 4096;                                    \
    load_lds16(aG0 + (KOFF), aB + (w * 32) * 32);                            \
    load_lds16(aG1 + (KOFF), aB + (w * 32 + 16) * 32);                       \
    load_lds16(bG0 + (KOFF), bB + (w * 32) * 32);                            \
    load_lds16(bG1 + (KOFF), bB + (w * 32 + 16) * 32);                       \
  }

  floatx4 acc[4][4] = {};

  GSTAGE(0, 0);
  GSTAGE(1, 32);

  for (int k0 = 0; k0 < 32; ++k0) {
    if (k0 < 31) {
      __asm__ __volatile__("s_waitcnt vmcnt(4)" ::: "memory");
    } else {
      __asm__ __volatile__("s_waitcnt vmcnt(0)" ::: "memory");
    }
    __asm__ __volatile__("s_barrier" ::: "memory");

    if (k0 < 30) {
      const int nx = (k0 + 2) % 3;
      GSTAGE(nx, (k0 + 2) * 32);
    }

    const int cur = k0 % 3;
    const bf16* A = smem + cur * 4096;
    const bf16* B = smem + 12288 + cur * 4096;

    bf16x8 af[4], bf[4];
#pragma unroll
    for (int i = 0; i < 4; ++i)
      af[i] = *(const bf16x8*)(A + (wm * 64 + i * 16 + l15) * 32 + quad * 8);
#pragma unroll
    for (int jj = 0; jj < 4; ++jj)
      bf[jj] = *(const bf16x8*)(B + (wn * 64 + jj * 16 + l15) * 32 + quad * 8);
#pragma unroll
    for (int i = 0; i < 4; ++i)
#pragma unroll
      for (int jj = 0; jj < 4; ++jj)
        acc[i][jj] = mfma16(af[i], bf[jj], acc[i][jj]);
  }
#undef GSTAGE

  __syncthreads();   // all waves done with LDS buffers before epilogue reuse

  // ---- epilogue: stage wave's 64x64 tile in LDS as the final memory image ----
  const size_t bhS = (size_t)T_SEQ * HD;
  bf16* pwv = smem + w * 4096;                       // 8KB per-wave buffer
  const int gm0 = m0 + wm * 64;
  const int t0w = gm0 & (T_SEQ - 1);
  const int bbw = gm0 >> 11;
  const int nl0 = (n0g + wn * 64) & (HDIM - 1);
  const int hw  = nl0 >> 6;
  bf16* obh = out + (size_t)(bbw * NH + hw) * bhS;

#pragma unroll
  for (int jj = 0; jj < 4; ++jj) {
    const int dl = jj * 16 + l15;                    // d_local 0..63
    const float bvv = bias[nl0 + dl];
#pragma unroll
    for (int i = 0; i < 4; ++i) {
#pragma unroll
      for (int r = 0; r < 4; ++r) {
        const int tl = i * 16 + quad * 4 + r;        // t_local 0..63
        const bf16 val = (bf16)(acc[i][jj][r] + bvv);
        int off;
        if (z == 0) {
          off = tl * 64 + dl;                        // Q row-major
        } else if (z == 1) {                         // K packed
          off = ((tl >> 5) << 11) + ((dl >> 4) << 9) +
                (((tl & 31) + (((dl >> 3) & 1) << 5)) << 3) + (dl & 7);
        } else {                                     // V packed (+T)
          off = ((tl >> 5) << 11) +
                ((((tl >> 4) & 1) + (((dl >> 5) & 1) << 1)) << 9) +
                (((dl & 31) + (((tl >> 3) & 1) << 5)) << 3) + (tl & 7);
        }
        pwv[off] = val;
      }
    }
  }
  __asm__ __volatile__("s_waitcnt lgkmcnt(0)" ::: "memory");

  const size_t gbase = (z == 0) ? (size_t)t0w * 64 : (size_t)(t0w >> 5) * 2048;
#pragma unroll
  for (int c = 0; c < 8; ++c)
    *(bf16x8*)(obh + gbase + c * 512 + lane * 8) =
        *(const bf16x8*)(pwv + c * 512 + lane * 8);
}

// ---------------------------------------------------------------------------
// Fallback QKV GEMM (fp32 staging, row-major output) for small workspaces.
// ---------------------------------------------------------------------------
#define LSTR 40

__global__ __launch_bounds__(256) void qkv_gemm_f32(
    const float* __restrict__ x,
    const float* __restrict__ Wq, const float* __restrict__ bq,
    const float* __restrict__ Wk, const float* __restrict__ bk,
    const float* __restrict__ Wv, const float* __restrict__ bv,
    bf16* __restrict__ qkv) {
  __shared__ __align__(16) bf16 As[128 * LSTR];
  __shared__ __align__(16) bf16 Bs[128 * LSTR];

  const int n0g = blockIdx.y * 128;
  const int z   = n0g >> 10;
  const int n0  = n0g & (HDIM - 1);
  const float* W    = (z == 0) ? Wq : (z == 1) ? Wk : Wv;
  const float* bias = (z == 0) ? bq : (z == 1) ? bk : bv;
  bf16* out = qkv + (size_t)z * BATCH * T_SEQ * HDIM;
  const int m0 = blockIdx.x * 128;

  const int lane = threadIdx.x & 63;
  const int w    = threadIdx.x >> 6;
  const int l15  = lane & 15;
  const int quad = lane >> 4;
  const int wm = w & 1, wn = w >> 1;

  const int srow  = threadIdx.x >> 1;
  const int shalf = threadIdx.x & 1;
  const float* aSrc = x + (size_t)(m0 + srow) * HDIM + shalf * 16;
  const float* bSrc = W + (size_t)(n0 + srow) * HDIM + shalf * 16;
  bf16* aDst = As + srow * LSTR + shalf * 16;
  bf16* bDst = Bs + srow * LSTR + shalf * 16;

  floatx4 acc[4][4] = {};

  for (int k0 = 0; k0 < HDIM; k0 += 32) {
    floatx4 a0 = *(const floatx4*)(aSrc + k0);
    floatx4 a1 = *(const floatx4*)(aSrc + k0 + 4);
    floatx4 a2 = *(const floatx4*)(aSrc + k0 + 8);
    floatx4 a3 = *(const floatx4*)(aSrc + k0 + 12);
    floatx4 b0 = *(const floatx4*)(bSrc + k0);
    floatx4 b1 = *(const floatx4*)(bSrc + k0 + 4);
    floatx4 b2 = *(const floatx4*)(bSrc + k0 + 8);
    floatx4 b3 = *(const floatx4*)(bSrc + k0 + 12);

    __syncthreads();
    *(bf16x8*)(aDst)     = cvt_pack(a0, a1);
    *(bf16x8*)(aDst + 8) = cvt_pack(a2, a3);
    *(bf16x8*)(bDst)     = cvt_pack(b0, b1);
    *(bf16x8*)(bDst + 8) = cvt_pack(b2, b3);
    __syncthreads();

    bf16x8 af[4], bff[4];
    for (int i = 0; i < 4; ++i)
      af[i] = *(const bf16x8*)(As + (wm * 64 + i * 16 + l15) * LSTR + quad * 8);
    for (int jj = 0; jj < 4; ++jj)
      bff[jj] = *(const bf16x8*)(Bs + (wn * 64 + jj * 16 + l15) * LSTR + quad * 8);
    for (int i = 0; i < 4; ++i)
      for (int jj = 0; jj < 4; ++jj)
        acc[i][jj] = mfma16(af[i], bff[jj], acc[i][jj]);
  }

  for (int jj = 0; jj < 4; ++jj) {
    const int nloc = n0 + wn * 64 + jj * 16 + l15;
    const float bvv = bias[nloc];
    const int h = nloc >> 6, d = nloc & (HD - 1);
    for (int i = 0; i < 4; ++i) {
      for (int r = 0; r < 4; ++r) {
        const int gm = m0 + wm * 64 + i * 16 + quad * 4 + r;
        const int bb = gm >> 11, t = gm & (T_SEQ - 1);
        out[((size_t)((bb * NH + h) * T_SEQ) + t) * HD + d] = (bf16)(acc[i][jj][r] + bvv);
      }
    }
  }
}

// ---------------------------------------------------------------------------
// Attention v15 (unchanged, verified): packed fragment loads, dual-tile
// window sharing, vectorized COMBINE stores.  grid (32, 16) x 256.
// ---------------------------------------------------------------------------
#define TBODY(QF, DIAG, O0, O1, LL)                                            \
  {                                                                            \
    floatx16 s = {};                                                           \
    s = mfma32(kf0, QF[0], s);                                                 \
    s = mfma32(kf1, QF[1], s);                                                 \
    s = mfma32(kf2, QF[2], s);                                                 \
    s = mfma32(kf3, QF[3], s);                                                 \
    float pp[16];                                                              \
    _Pragma("unroll")                                                          \
    for (int r = 0; r < 16; ++r) pp[r] = __expf(s[r]);                         \
    if (DIAG) {                                                                \
      _Pragma("unroll")                                                        \
      for (int r = 0; r < 16; ++r) {                                           \
        const int krow = (r & 3) + 8 * (r >> 2) + 4 * hf;                      \
        if (krow > l31) pp[r] = 0.f;                                           \
      }                                                                        \
    }                                                                          \
    float psum = 0.f;                                                          \
    _Pragma("unroll")                                                          \
    for (int r = 0; r < 16; ++r) psum += pp[r];                                \
    LL += psum;                                                                \
    unsigned int Dg[4][2], Xg[4][2];                                           \
    _Pragma("unroll")                                                          \
    for (int a = 0; a < 4; ++a) {                                              \
      Dg[a][0] = packbf(pp[4 * a + 0], pp[4 * a + 1]);                         \
      Dg[a][1] = packbf(pp[4 * a + 2], pp[4 * a + 3]);                         \
    }                                                                          \
    _Pragma("unroll")                                                          \
    for (int a = 0; a < 4; ++a) {                                              \
      Xg[a][0] = (unsigned int)__shfl_xor((int)Dg[a][0], 32, 64);              \
      Xg[a][1] = (unsigned int)__shfl_xor((int)Dg[a][1], 32, 64);              \
    }                                                                          \
    uintx4 f0u, f1u;                                                           \
    f0u[0] = hf ? Xg[1][0] : Dg[0][0];                                         \
    f0u[1] = hf ? Xg[1][1] : Dg[0][1];                                         \
    f0u[2] = hf ? Dg[1][0] : Xg[0][0];                                         \
    f0u[3] = hf ? Dg[1][1] : Xg[0][1];                                         \
    f1u[0] = hf ? Xg[3][0] : Dg[2][0];                                         \
    f1u[1] = hf ? Xg[3][1] : Dg[2][1];                                         \
    f1u[2] = hf ? Dg[3][0] : Xg[2][0];                                         \
    f1u[3] = hf ? Dg[3][1] : Xg[2][1];                                         \
    bf16x8 pf0 = __builtin_bit_cast(bf16x8, f0u);                              \
    bf16x8 pf1 = __builtin_bit_cast(bf16x8, f1u);                              \
    O0 = mfma32(v00, pf0, O0);                                                 \
    O0 = mfma32(v01, pf1, O0);                                                 \
    O1 = mfma32(v10, pf0, O1);                                                 \
    O1 = mfma32(v11, pf1, O1);                                                 \
  }

// one window, two tiles (tile0 = T0, tile1 = T0+1); skip tile0 past its range
#define ASTEP2(G, T0, QF0a, QF1a)                                              \
  {                                                                            \
    const int g_ = (G);                                                        \
    const bf16* kp_ = Kb + g_ * 2048 + lane * 8;                               \
    bf16x8 kf0 = *(const bf16x8*)(kp_);                                        \
    bf16x8 kf1 = *(const bf16x8*)(kp_ + 512);                                  \
    bf16x8 kf2 = *(const bf16x8*)(kp_ + 1024);                                 \
    bf16x8 kf3 = *(const bf16x8*)(kp_ + 1536);                                 \
    const bf16* vp_ = Vb + g_ * 2048 + lane * 8;                               \
    bf16x8 v00 = *(const bf16x8*)(vp_);                                        \
    bf16x8 v01 = *(const bf16x8*)(vp_ + 512);                                  \
    bf16x8 v10 = *(const bf16x8*)(vp_ + 1024);                                 \
    bf16x8 v11 = *(const bf16x8*)(vp_ + 1536);                                 \
    if (g_ <= (T0)) TBODY(QF0a, g_ == (T0), o00, o01, l0);                     \
    TBODY(QF1a, g_ == (T0) + 1, o10, o11, l1);                                 \
  }

// combine one tile's partials across 4 waves; vectorized coalesced stores
#define COMBINE(O0, O1, LL, QBASE)                                             \
  {                                                                            \
    _Pragma("unroll")                                                          \
    for (int r = 0; r < 16; ++r) {                                             \
      ps[w][lane][r]      = O0[r];                                             \
      ps[w][lane][16 + r] = O1[r];                                             \
    }                                                                          \
    ps[w][lane][32] = LL;                                                      \
    __syncthreads();                                                           \
    const int ql = threadIdx.x >> 3;                                           \
    const int ch = threadIdx.x & 7;                                            \
    const float ls = ps[0][ql][32] + ps[1][ql][32] +                           \
                     ps[2][ql][32] + ps[3][ql][32];                            \
    const float inv = 1.f / ls;                                                \
    float ov[8];                                                               \
    _Pragma("unroll")                                                          \
    for (int e = 0; e < 8; ++e) {                                              \
      const int d  = ch * 8 + e;                                               \
      const int dp = d & 31;                                                   \
      const int lsrc = ql + (((dp >> 2) & 1) << 5);                            \
      const int rr = (dp & 3) + ((dp >> 3) << 2) + ((d >> 5) << 4);            \
      ov[e] = (ps[0][lsrc][rr] + ps[1][lsrc][rr] +                             \
               ps[2][lsrc][rr] + ps[3][lsrc][rr]) * inv;                       \
    }                                                                          \
    float* ob = out + ((size_t)(b * T_SEQ + (QBASE) + ql)) * HDIM +            \
                hh * HD + ch * 8;                                              \
    floatx4 v0_ = {ov[0], ov[1], ov[2], ov[3]};                                \
    floatx4 v1_ = {ov[4], ov[5], ov[6], ov[7]};                                \
    *(floatx4*)(ob)     = v0_;                                                 \
    *(floatx4*)(ob + 4) = v1_;                                                 \
  }

__global__ __launch_bounds__(256, 2) void attn_v15(
    const bf16* __restrict__ qkv, float* __restrict__ out) {
  __shared__ float ps[4][64][33];   // 33792 B partial-combine buffer

  const int lane = threadIdx.x & 63;
  const int w    = threadIdx.x >> 6;
  const int l31  = lane & 31;
  const int hf   = lane >> 5;

  // XCD-locality remap (bijective over 512 blocks)
  const int lin = blockIdx.x + (blockIdx.y << 5);
  const int bh  = ((lin & 7) << 2) + ((lin >> 3) & 3);
  const int p   = lin >> 5;             // 0..15

  const int a0 = 2 * p;                 // A tiles {a0, a0+1}
  const int b0 = 62 - 2 * p;            // B tiles {b0, b0+1}
  const int NA = 2 * p + 2;             // A windows; NA + NB == 66

  const bf16* Qb = qkv + (size_t)bh * T_SEQ * HD;
  const bf16* Kb = qkv + (size_t)BATCH * T_SEQ * HDIM + (size_t)bh * T_SEQ * HD;
  const bf16* Vb = qkv + (size_t)2 * BATCH * T_SEQ * HDIM + (size_t)bh * T_SEQ * HD;
  const int b = bh >> 4, hh = bh & (NH - 1);

  bf16x8 qf0[4], qf1[4];
  floatx16 o00, o01, o10, o11;
  float l0, l1;
  int m = w;

  // ================= A group: tiles a0, a0+1 =================
#pragma unroll
  for (int kk = 0; kk < 4; ++kk) {
    qf0[kk] = *(const bf16x8*)(Qb + (size_t)(a0 * 32 + l31) * HD + kk * 16 + hf * 8);
    qf1[kk] = *(const bf16x8*)(Qb + (size_t)(a0 * 32 + 32 + l31) * HD + kk * 16 + hf * 8);
#pragma unroll
    for (int e = 0; e < 8; ++e) {
      qf0[kk][e] = (bf16)((float)qf0[kk][e] * SCALE);
      qf1[kk][e] = (bf16)((float)qf1[kk][e] * SCALE);
    }
  }
  o00 = (floatx16){}; o01 = (floatx16){};
  o10 = (floatx16){}; o11 = (floatx16){};
  l0 = 0.f; l1 = 0.f;

  for (; m < NA; m += 4)
    ASTEP2(m, a0, qf0, qf1);

  l0 += __shfl_xor(l0, 32, 64);
  l1 += __shfl_xor(l1, 32, 64);

  COMBINE(o00, o01, l0, a0 * 32);
  __syncthreads();
  COMBINE(o10, o11, l1, a0 * 32 + 32);
  __syncthreads();

  // ================= B group: tiles b0, b0+1 =================
#pragma unroll
  for (int kk = 0; kk < 4; ++kk) {
    qf0[kk] = *(const bf16x8*)(Qb + (size_t)(b0 * 32 + l31) * HD + kk * 16 + hf * 8);
    qf1[kk] = *(const bf16x8*)(Qb + (size_t)(b0 * 32 + 32 + l31) * HD + kk * 16 + hf * 8);
#pragma unroll
    for (int e = 0; e < 8; ++e) {
      qf0[kk][e] = (bf16)((float)qf0[kk][e] * SCALE);
      qf1[kk][e] = (bf16)((float)qf1[kk][e] * SCALE);
    }
  }
  o00 = (floatx16){}; o01 = (floatx16){};
  o10 = (floatx16){}; o11 = (floatx16){};
  l0 = 0.f; l1 = 0.f;

  for (; m < 66; m += 4)
    ASTEP2(m - NA, b0, qf0, qf1);

  l0 += __shfl_xor(l0, 32, 64);
  l1 += __shfl_xor(l1, 32, 64);

  COMBINE(o00, o01, l0, b0 * 32);
  __syncthreads();
  COMBINE(o10, o11, l1, b0 * 32 + 32);
}

// ---------------------------------------------------------------------------
// Attention v4 (row-major K/V) — kept as fallback for small workspaces.
// ---------------------------------------------------------------------------
#define PSTR 40

__global__ __launch_bounds__(256) void attn_v4(
    const bf16* __restrict__ qkv, float* __restrict__ out) {
  const bf16* Q = qkv;
  const bf16* K = qkv + (size_t)BATCH * T_SEQ * HDIM;
  const bf16* V = K + (size_t)BATCH * T_SEQ * HDIM;

  __shared__ __align__(16) bf16 pl[4 * 16 * PSTR];

  const int lane = threadIdx.x & 63;
  const int w    = threadIdx.x >> 6;
  const int l15  = lane & 15;
  const int quad = lane >> 4;

  const int bh = blockIdx.x;
  const int j  = blockIdx.y;
  const bf16* Qb = Q + (size_t)bh * T_SEQ * HD;
  const bf16* Kb = K + (size_t)bh * T_SEQ * HD;
  const bf16* Vb = V + (size_t)bh * T_SEQ * HD;
  const int b = bh >> 4, h = bh & (NH - 1);

  const int qt = (w == 0) ? j : (w == 1) ? (63 - j) : (w == 2) ? (64 + j) : (127 - j);
  const int q0 = qt * 16;

  bf16* pw = pl + w * 16 * PSTR;

  bf16x8 qf0 = *(const bf16x8*)(Qb + (size_t)(q0 + l15) * HD + quad * 8);
  bf16x8 qf1 = *(const bf16x8*)(Qb + (size_t)(q0 + l15) * HD + 32 + quad * 8);
  for (int e = 0; e < 8; ++e) {
    qf0[e] = (bf16)((float)qf0[e] * SCALE);
    qf1[e] = (bf16)((float)qf1[e] * SCALE);
  }

  floatx4 o[4] = {};
  float lacc[4] = {0.f, 0.f, 0.f, 0.f};

  const int S = (qt >> 1) + 1;

  for (int s0 = 0; s0 < S; ++s0) {
    const int kv = s0 * 32;

    bf16 ve[4][8];
    for (int jjj = 0; jjj < 8; ++jjj) {
      const bf16* vrow = Vb + (size_t)(kv + quad * 8 + jjj) * HD + l15;
      for (int dt = 0; dt < 4; ++dt) ve[dt][jjj] = vrow[dt * 16];
    }

    floatx4 sa[2];
    for (int nt = 0; nt < 2; ++nt) {
      const int kbase = kv + nt * 16;
      bf16x8 k0 = *(const bf16x8*)(Kb + (size_t)(kbase + l15) * HD + quad * 8);
      bf16x8 k1 = *(const bf16x8*)(Kb + (size_t)(kbase + l15) * HD + 32 + quad * 8);
      floatx4 s = {};
      s = mfma16(qf0, k0, s);
      s = mfma16(qf1, k1, s);
      sa[nt] = s;
    }

    float p[2][4];
    for (int nt = 0; nt < 2; ++nt)
      for (int r = 0; r < 4; ++r) p[nt][r] = __expf(sa[nt][r]);
    if (s0 == S - 1) {
      for (int nt = 0; nt < 2; ++nt) {
        const int kg = kv + nt * 16 + l15;
        for (int r = 0; r < 4; ++r) {
          const int qg = q0 + quad * 4 + r;
          if (kg > qg) p[nt][r] = 0.f;
        }
      }
    }
    for (int r = 0; r < 4; ++r) lacc[r] += p[0][r] + p[1][r];

    for (int nt = 0; nt < 2; ++nt)
      for (int r = 0; r < 4; ++r)
        pw[(quad * 4 + r) * PSTR + nt * 16 + l15] = (bf16)p[nt][r];
    __asm__ __volatile__("s_waitcnt lgkmcnt(0)" ::: "memory");
    const bf16x8 pf = *(const bf16x8*)(pw + l15 * PSTR + quad * 8);

    for (int dt = 0; dt < 4; ++dt) {
      bf16x8 vf;
      for (int jjj = 0; jjj < 8; ++jjj) vf[jjj] = ve[dt][jjj];
      o[dt] = mfma16(pf, vf, o[dt]);
    }
  }

  for (int r = 0; r < 4; ++r) {
    float v = lacc[r];
    for (int off = 1; off < 16; off <<= 1) v += __shfl_xor(v, off, 64);
    lacc[r] = v;
  }

  for (int dt = 0; dt < 4; ++dt) {
    for (int r = 0; r < 4; ++r) {
      const int t = q0 + quad * 4 + r;
      out[((size_t)(b * T_SEQ + t) * HDIM) + h * HD + dt * 16 + l15] =
          o[dt][r] / lacc[r];
    }
  }
}

// ---------------------------------------------------------------------------
extern "C" void kernel_launch(void* const* d_in, const int* in_sizes, int n_in,
                              void* d_out, int out_size, void* d_ws, size_t ws_size,
                              hipStream_t stream) {
  const float* x  = (const float*)d_in[0];
  const float* Wq = (const float*)d_in[1];
  const float* bq = (const float*)d_in[2];
  const float* Wk = (const float*)d_in[3];
  const float* bk = (const float*)d_in[4];
  const float* Wv = (const float*)d_in[5];
  const float* bv = (const float*)d_in[6];
  float* out = (float*)d_out;

  const size_t elems = (size_t)BATCH * T_SEQ * HDIM;   // 4M
  bf16* qkv  = (bf16*)d_ws;                            // 24 MB (Q | Kpack | Vpack)
  bf16* xbuf = qkv + 3 * elems;                        // +8 MB (x bf16)
  bf16* wbuf = xbuf + elems;                           // +6 MB (W bf16)

  const bool fast = ws_size >= (size_t)39 * 1024 * 1024;
  dim3 g1(BATCH * T_SEQ / 128, 3 * HDIM / 128);
  if (fast) {
    cvt_f32_bf16<<<dim3(4096, 4), 256, 0, stream>>>(x, Wq, Wk, Wv, xbuf, wbuf);
    qkv_gemm_lds<<<g1, 256, 0, stream>>>(xbuf, wbuf, bq, bk, bv, qkv);
    attn_v15<<<dim3(32, 16), 256, 0, stream>>>(qkv, out);
  } else {
    qkv_gemm_f32<<<g1, 256, 0, stream>>>(x, Wq, bq, Wk, bk, Wv, bv, qkv);
    attn_v4<<<dim3(BATCH * NH, 32), 256, 0, stream>>>(qkv, out);
  }
}

// Round 16
// 148.389 us; speedup vs baseline: 1.0357x; 1.0357x over previous
//
#include <hip/hip_runtime.h>
#include <math.h>

typedef __bf16 bf16;
typedef __bf16 bf16x8 __attribute__((ext_vector_type(8)));
typedef __bf16 bf16x4 __attribute__((ext_vector_type(4)));
typedef __bf16 bf16x2 __attribute__((ext_vector_type(2)));
typedef float floatx4 __attribute__((ext_vector_type(4)));
typedef float floatx16 __attribute__((ext_vector_type(16)));
typedef unsigned int uintx4 __attribute__((ext_vector_type(4)));

#define T_SEQ 2048
#define NH 16
#define HD 64
#define HDIM 1024
#define BATCH 2
#define SCALE 0.03125f  // 1/sqrt(1024) per reference

static __device__ __forceinline__ floatx4 mfma16(bf16x8 a, bf16x8 b, floatx4 c) {
  return __builtin_amdgcn_mfma_f32_16x16x32_bf16(a, b, c, 0, 0, 0);
}
static __device__ __forceinline__ floatx16 mfma32(bf16x8 a, bf16x8 b, floatx16 c) {
  return __builtin_amdgcn_mfma_f32_32x32x16_bf16(a, b, c, 0, 0, 0);
}

static __device__ __forceinline__ unsigned int packbf(float a, float b) {
  bf16x2 t; t[0] = (bf16)a; t[1] = (bf16)b;
  return __builtin_bit_cast(unsigned int, t);
}

static __device__ __forceinline__ bf16x8 cvt_pack(floatx4 lo, floatx4 hi) {
  bf16x8 r;
  r[0] = (bf16)lo[0]; r[1] = (bf16)lo[1]; r[2] = (bf16)lo[2]; r[3] = (bf16)lo[3];
  r[4] = (bf16)hi[0]; r[5] = (bf16)hi[1]; r[6] = (bf16)hi[2]; r[7] = (bf16)hi[3];
  return r;
}

typedef const __attribute__((address_space(1))) void* gas_ptr;
typedef __attribute__((address_space(3))) void* las_ptr;
static __device__ __forceinline__ void load_lds16(const bf16* g, bf16* l) {
  __builtin_amdgcn_global_load_lds((gas_ptr)g, (las_ptr)l, 16, 0, 0);
}

// ---------------------------------------------------------------------------
// cvt v2: grid-stride, 2048 blocks (was 16384 -- launch-overhead-bound).
// Flat space: x (4M elems) -> xb, then Wq|Wk|Wv (1M each) -> wb.
// Each thread converts 4 elems per chunk, grid-strided.
// ---------------------------------------------------------------------------
__global__ __launch_bounds__(256) void cvt_f32_bf16(
    const float* __restrict__ x, const float* __restrict__ Wq,
    const float* __restrict__ Wk, const float* __restrict__ Wv,
    bf16* __restrict__ xb, bf16* __restrict__ wb) {
  const size_t XN = (size_t)BATCH * T_SEQ * HDIM;   // 4M
  const size_t WN = (size_t)HDIM * HDIM;            // 1M
  const size_t TOT4 = (XN + 3 * WN) / 4;            // 1.75M chunks of 4
  const size_t stride = (size_t)gridDim.x * 256;

  for (size_t c = blockIdx.x * 256 + threadIdx.x; c < TOT4; c += stride) {
    const size_t i4 = c * 4;
    const float* src; bf16* dst; size_t off;
    if (i4 < XN)                { src = x;  dst = xb;           off = i4; }
    else if (i4 < XN + WN)      { src = Wq; dst = wb;           off = i4 - XN; }
    else if (i4 < XN + 2 * WN)  { src = Wk; dst = wb + WN;      off = i4 - XN - WN; }
    else                        { src = Wv; dst = wb + 2 * WN;  off = i4 - XN - 2 * WN; }
    floatx4 v = *(const floatx4*)(src + off);
    bf16x4 o; o[0]=(bf16)v[0]; o[1]=(bf16)v[1]; o[2]=(bf16)v[2]; o[3]=(bf16)v[3];
    *(bf16x4*)(dst + off) = o;
  }
}

// ---------------------------------------------------------------------------
// QKV GEMM v5 (R13-verified best): BK=32 double-buffer pipeline + LDS-staged
// vector epilogue with PACKED K/V layout.
//   Kpack elem (t,d) -> (t>>5)*2048 + (d>>4)*512 + ((t&31)+32*((d>>3)&1))*8 + (d&7)
//   Vpack elem (t,d) -> (t>>5)*2048 + (((t>>4)&1)+2*(d>>5))*512
//                        + ((d&31)+32*((t>>3)&1))*8 + (t&7)
// grid (32, 24) x 256.
// ---------------------------------------------------------------------------
__global__ __launch_bounds__(256) void qkv_gemm_lds(
    const bf16* __restrict__ xb, const bf16* __restrict__ wb,
    const float* __restrict__ bq, const float* __restrict__ bk,
    const float* __restrict__ bv, bf16* __restrict__ qkv) {
  __shared__ __align__(16) bf16 smem[16384];   // 32 KB

  const int m0  = blockIdx.x * 128;
  const int n0g = blockIdx.y * 128;
  const int z   = n0g >> 10;
  const float* bias = (z == 0) ? bq : (z == 1) ? bk : bv;
  bf16* out = qkv + (size_t)z * BATCH * T_SEQ * HDIM;

  const int lane = threadIdx.x & 63;
  const int w    = threadIdx.x >> 6;
  const int l15  = lane & 15;
  const int quad = lane >> 4;
  const int wm = w & 1, wn = w >> 1;

  const int srow = w * 32 + (lane >> 2);
  const int scol = (lane & 3) * 8;
  const bf16* aG0 = xb + (size_t)(m0 + srow) * HDIM + scol;
  const bf16* aG1 = xb + (size_t)(m0 + srow + 16) * HDIM + scol;
  const bf16* bG0 = wb + (size_t)(n0g + srow) * HDIM + scol;
  const bf16* bG1 = wb + (size_t)(n0g + srow + 16) * HDIM + scol;

#define GSTAGE(BUF, KOFF)                                                    \
  {                                                                          \
    bf16* aB = smem + (BUF) * 4096;                                          \
    bf16* bB = smem + 8192 + (BUF) * 4096;                                   \
    load_lds16(aG0 + (KOFF), aB + (w * 32) * 32);                            \
    load_lds16(aG1 + (KOFF), aB + (w * 32 + 16) * 32);                       \
    load_lds16(bG0 + (KOFF), bB + (w * 32) * 32);                            \
    load_lds16(bG1 + (KOFF), bB + (w * 32 + 16) * 32);                       \
  }

  floatx4 acc[4][4] = {};

  GSTAGE(0, 0);
  __syncthreads();

  for (int k0 = 0; k0 < 32; ++k0) {
    const int cur = k0 & 1;
    if (k0 < 31) GSTAGE(cur ^ 1, (k0 + 1) * 32);

    const bf16* A = smem + cur * 4096;
    const bf16* B = smem + 8192 + cur * 4096;

    bf16x8 af[4], bf[4];
#pragma unroll
    for (int i = 0; i < 4; ++i)
      af[i] = *(const bf16x8*)(A + (wm * 64 + i * 16 + l15) * 32 + quad * 8);
#pragma unroll
    for (int jj = 0; jj < 4; ++jj)
      bf[jj] = *(const bf16x8*)(B + (wn * 64 + jj * 16 + l15) * 32 + quad * 8);
#pragma unroll
    for (int i = 0; i < 4; ++i)
#pragma unroll
      for (int jj = 0; jj < 4; ++jj)
        acc[i][jj] = mfma16(af[i], bf[jj], acc[i][jj]);

    __syncthreads();
  }
#undef GSTAGE

  // ---- epilogue: stage wave's 64x64 tile in LDS as the final memory image ----
  const size_t bhS = (size_t)T_SEQ * HD;
  bf16* pwv = smem + w * 4096;                       // 8KB per-wave buffer
  const int gm0 = m0 + wm * 64;
  const int t0w = gm0 & (T_SEQ - 1);
  const int bbw = gm0 >> 11;
  const int nl0 = (n0g + wn * 64) & (HDIM - 1);
  const int hw  = nl0 >> 6;
  bf16* obh = out + (size_t)(bbw * NH + hw) * bhS;

#pragma unroll
  for (int jj = 0; jj < 4; ++jj) {
    const int dl = jj * 16 + l15;                    // d_local 0..63
    const float bvv = bias[nl0 + dl];
#pragma unroll
    for (int i = 0; i < 4; ++i) {
#pragma unroll
      for (int r = 0; r < 4; ++r) {
        const int tl = i * 16 + quad * 4 + r;        // t_local 0..63
        const bf16 val = (bf16)(acc[i][jj][r] + bvv);
        int off;
        if (z == 0) {
          off = tl * 64 + dl;                        // Q row-major
        } else if (z == 1) {                         // K packed
          off = ((tl >> 5) << 11) + ((dl >> 4) << 9) +
                (((tl & 31) + (((dl >> 3) & 1) << 5)) << 3) + (dl & 7);
        } else {                                     // V packed (+T)
          off = ((tl >> 5) << 11) +
                ((((tl >> 4) & 1) + (((dl >> 5) & 1) << 1)) << 9) +
                (((dl & 31) + (((tl >> 3) & 1) << 5)) << 3) + (tl & 7);
        }
        pwv[off] = val;
      }
    }
  }
  __asm__ __volatile__("s_waitcnt lgkmcnt(0)" ::: "memory");

  const size_t gbase = (z == 0) ? (size_t)t0w * 64 : (size_t)(t0w >> 5) * 2048;
#pragma unroll
  for (int c = 0; c < 8; ++c)
    *(bf16x8*)(obh + gbase + c * 512 + lane * 8) =
        *(const bf16x8*)(pwv + c * 512 + lane * 8);
}

// ---------------------------------------------------------------------------
// Fallback QKV GEMM (fp32 staging, row-major output) for small workspaces.
// ---------------------------------------------------------------------------
#define LSTR 40

__global__ __launch_bounds__(256) void qkv_gemm_f32(
    const float* __restrict__ x,
    const float* __restrict__ Wq, const float* __restrict__ bq,
    const float* __restrict__ Wk, const float* __restrict__ bk,
    const float* __restrict__ Wv, const float* __restrict__ bv,
    bf16* __restrict__ qkv) {
  __shared__ __align__(16) bf16 As[128 * LSTR];
  __shared__ __align__(16) bf16 Bs[128 * LSTR];

  const int n0g = blockIdx.y * 128;
  const int z   = n0g >> 10;
  const int n0  = n0g & (HDIM - 1);
  const float* W    = (z == 0) ? Wq : (z == 1) ? Wk : Wv;
  const float* bias = (z == 0) ? bq : (z == 1) ? bk : bv;
  bf16* out = qkv + (size_t)z * BATCH * T_SEQ * HDIM;
  const int m0 = blockIdx.x * 128;

  const int lane = threadIdx.x & 63;
  const int w    = threadIdx.x >> 6;
  const int l15  = lane & 15;
  const int quad = lane >> 4;
  const int wm = w & 1, wn = w >> 1;

  const int srow  = threadIdx.x >> 1;
  const int shalf = threadIdx.x & 1;
  const float* aSrc = x + (size_t)(m0 + srow) * HDIM + shalf * 16;
  const float* bSrc = W + (size_t)(n0 + srow) * HDIM + shalf * 16;
  bf16* aDst = As + srow * LSTR + shalf * 16;
  bf16* bDst = Bs + srow * LSTR + shalf * 16;

  floatx4 acc[4][4] = {};

  for (int k0 = 0; k0 < HDIM; k0 += 32) {
    floatx4 a0 = *(const floatx4*)(aSrc + k0);
    floatx4 a1 = *(const floatx4*)(aSrc + k0 + 4);
    floatx4 a2 = *(const floatx4*)(aSrc + k0 + 8);
    floatx4 a3 = *(const floatx4*)(aSrc + k0 + 12);
    floatx4 b0 = *(const floatx4*)(bSrc + k0);
    floatx4 b1 = *(const floatx4*)(bSrc + k0 + 4);
    floatx4 b2 = *(const floatx4*)(bSrc + k0 + 8);
    floatx4 b3 = *(const floatx4*)(bSrc + k0 + 12);

    __syncthreads();
    *(bf16x8*)(aDst)     = cvt_pack(a0, a1);
    *(bf16x8*)(aDst + 8) = cvt_pack(a2, a3);
    *(bf16x8*)(bDst)     = cvt_pack(b0, b1);
    *(bf16x8*)(bDst + 8) = cvt_pack(b2, b3);
    __syncthreads();

    bf16x8 af[4], bff[4];
    for (int i = 0; i < 4; ++i)
      af[i] = *(const bf16x8*)(As + (wm * 64 + i * 16 + l15) * LSTR + quad * 8);
    for (int jj = 0; jj < 4; ++jj)
      bff[jj] = *(const bf16x8*)(Bs + (wn * 64 + jj * 16 + l15) * LSTR + quad * 8);
    for (int i = 0; i < 4; ++i)
      for (int jj = 0; jj < 4; ++jj)
        acc[i][jj] = mfma16(af[i], bff[jj], acc[i][jj]);
  }

  for (int jj = 0; jj < 4; ++jj) {
    const int nloc = n0 + wn * 64 + jj * 16 + l15;
    const float bvv = bias[nloc];
    const int h = nloc >> 6, d = nloc & (HD - 1);
    for (int i = 0; i < 4; ++i) {
      for (int r = 0; r < 4; ++r) {
        const int gm = m0 + wm * 64 + i * 16 + quad * 4 + r;
        const int bb = gm >> 11, t = gm & (T_SEQ - 1);
        out[((size_t)((bb * NH + h) * T_SEQ) + t) * HD + d] = (bf16)(acc[i][jj][r] + bvv);
      }
    }
  }
}

// ---------------------------------------------------------------------------
// Attention v15 (R13-verified): packed fragment loads, dual-tile window
// sharing, vectorized COMBINE stores.  grid (32, 16) x 256.
// ---------------------------------------------------------------------------
#define TBODY(QF, DIAG, O0, O1, LL)                                            \
  {                                                                            \
    floatx16 s = {};                                                           \
    s = mfma32(kf0, QF[0], s);                                                 \
    s = mfma32(kf1, QF[1], s);                                                 \
    s = mfma32(kf2, QF[2], s);                                                 \
    s = mfma32(kf3, QF[3], s);                                                 \
    float pp[16];                                                              \
    _Pragma("unroll")                                                          \
    for (int r = 0; r < 16; ++r) pp[r] = __expf(s[r]);                         \
    if (DIAG) {                                                                \
      _Pragma("unroll")                                                        \
      for (int r = 0; r < 16; ++r) {                                           \
        const int krow = (r & 3) + 8 * (r >> 2) + 4 * hf;                      \
        if (krow > l31) pp[r] = 0.f;                                           \
      }                                                                        \
    }                                                                          \
    float psum = 0.f;                                                          \
    _Pragma("unroll")                                                          \
    for (int r = 0; r < 16; ++r) psum += pp[r];                                \
    LL += psum;                                                                \
    unsigned int Dg[4][2], Xg[4][2];                                           \
    _Pragma("unroll")                                                          \
    for (int a = 0; a < 4; ++a) {                                              \
      Dg[a][0] = packbf(pp[4 * a + 0], pp[4 * a + 1]);                         \
      Dg[a][1] = packbf(pp[4 * a + 2], pp[4 * a + 3]);                         \
    }                                                                          \
    _Pragma("unroll")                                                          \
    for (int a = 0; a < 4; ++a) {                                              \
      Xg[a][0] = (unsigned int)__shfl_xor((int)Dg[a][0], 32, 64);              \
      Xg[a][1] = (unsigned int)__shfl_xor((int)Dg[a][1], 32, 64);              \
    }                                                                          \
    uintx4 f0u, f1u;                                                           \
    f0u[0] = hf ? Xg[1][0] : Dg[0][0];                                         \
    f0u[1] = hf ? Xg[1][1] : Dg[0][1];                                         \
    f0u[2] = hf ? Dg[1][0] : Xg[0][0];                                         \
    f0u[3] = hf ? Dg[1][1] : Xg[0][1];                                         \
    f1u[0] = hf ? Xg[3][0] : Dg[2][0];                                         \
    f1u[1] = hf ? Xg[3][1] : Dg[2][1];                                         \
    f1u[2] = hf ? Dg[3][0] : Xg[2][0];                                         \
    f1u[3] = hf ? Dg[3][1] : Xg[2][1];                                         \
    bf16x8 pf0 = __builtin_bit_cast(bf16x8, f0u);                              \
    bf16x8 pf1 = __builtin_bit_cast(bf16x8, f1u);                              \
    O0 = mfma32(v00, pf0, O0);                                                 \
    O0 = mfma32(v01, pf1, O0);                                                 \
    O1 = mfma32(v10, pf0, O1);                                                 \
    O1 = mfma32(v11, pf1, O1);                                                 \
  }

// one window, two tiles (tile0 = T0, tile1 = T0+1); skip tile0 past its range
#define ASTEP2(G, T0, QF0a, QF1a)                                              \
  {                                                                            \
    const int g_ = (G);                                                        \
    const bf16* kp_ = Kb + g_ * 2048 + lane * 8;                               \
    bf16x8 kf0 = *(const bf16x8*)(kp_);                                        \
    bf16x8 kf1 = *(const bf16x8*)(kp_ + 512);                                  \
    bf16x8 kf2 = *(const bf16x8*)(kp_ + 1024);                                 \
    bf16x8 kf3 = *(const bf16x8*)(kp_ + 1536);                                 \
    const bf16* vp_ = Vb + g_ * 2048 + lane * 8;                               \
    bf16x8 v00 = *(const bf16x8*)(vp_);                                        \
    bf16x8 v01 = *(const bf16x8*)(vp_ + 512);                                  \
    bf16x8 v10 = *(const bf16x8*)(vp_ + 1024);                                 \
    bf16x8 v11 = *(const bf16x8*)(vp_ + 1536);                                 \
    if (g_ <= (T0)) TBODY(QF0a, g_ == (T0), o00, o01, l0);                     \
    TBODY(QF1a, g_ == (T0) + 1, o10, o11, l1);                                 \
  }

// combine one tile's partials across 4 waves; vectorized coalesced stores
#define COMBINE(O0, O1, LL, QBASE)                                             \
  {                                                                            \
    _Pragma("unroll")                                                          \
    for (int r = 0; r < 16; ++r) {                                             \
      ps[w][lane][r]      = O0[r];                                             \
      ps[w][lane][16 + r] = O1[r];                                             \
    }                                                                          \
    ps[w][lane][32] = LL;                                                      \
    __syncthreads();                                                           \
    const int ql = threadIdx.x >> 3;                                           \
    const int ch = threadIdx.x & 7;                                            \
    const float ls = ps[0][ql][32] + ps[1][ql][32] +                           \
                     ps[2][ql][32] + ps[3][ql][32];                            \
    const float inv = 1.f / ls;                                                \
    float ov[8];                                                               \
    _Pragma("unroll")                                                          \
    for (int e = 0; e < 8; ++e) {                                              \
      const int d  = ch * 8 + e;                                               \
      const int dp = d & 31;                                                   \
      const int lsrc = ql + (((dp >> 2) & 1) << 5);                            \
      const int rr = (dp & 3) + ((dp >> 3) << 2) + ((d >> 5) << 4);            \
      ov[e] = (ps[0][lsrc][rr] + ps[1][lsrc][rr] +                             \
               ps[2][lsrc][rr] + ps[3][lsrc][rr]) * inv;                       \
    }                                                                          \
    float* ob = out + ((size_t)(b * T_SEQ + (QBASE) + ql)) * HDIM +            \
                hh * HD + ch * 8;                                              \
    floatx4 v0_ = {ov[0], ov[1], ov[2], ov[3]};                                \
    floatx4 v1_ = {ov[4], ov[5], ov[6], ov[7]};                                \
    *(floatx4*)(ob)     = v0_;                                                 \
    *(floatx4*)(ob + 4) = v1_;                                                 \
  }

__global__ __launch_bounds__(256, 2) void attn_v15(
    const bf16* __restrict__ qkv, float* __restrict__ out) {
  __shared__ float ps[4][64][33];   // 33792 B partial-combine buffer

  const int lane = threadIdx.x & 63;
  const int w    = threadIdx.x >> 6;
  const int l31  = lane & 31;
  const int hf   = lane >> 5;

  // XCD-locality remap (bijective over 512 blocks)
  const int lin = blockIdx.x + (blockIdx.y << 5);
  const int bh  = ((lin & 7) << 2) + ((lin >> 3) & 3);
  const int p   = lin >> 5;             // 0..15

  const int a0 = 2 * p;                 // A tiles {a0, a0+1}
  const int b0 = 62 - 2 * p;            // B tiles {b0, b0+1}
  const int NA = 2 * p + 2;             // A windows; NA + NB == 66

  const bf16* Qb = qkv + (size_t)bh * T_SEQ * HD;
  const bf16* Kb = qkv + (size_t)BATCH * T_SEQ * HDIM + (size_t)bh * T_SEQ * HD;
  const bf16* Vb = qkv + (size_t)2 * BATCH * T_SEQ * HDIM + (size_t)bh * T_SEQ * HD;
  const int b = bh >> 4, hh = bh & (NH - 1);

  bf16x8 qf0[4], qf1[4];
  floatx16 o00, o01, o10, o11;
  float l0, l1;
  int m = w;

  // ================= A group: tiles a0, a0+1 =================
#pragma unroll
  for (int kk = 0; kk < 4; ++kk) {
    qf0[kk] = *(const bf16x8*)(Qb + (size_t)(a0 * 32 + l31) * HD + kk * 16 + hf * 8);
    qf1[kk] = *(const bf16x8*)(Qb + (size_t)(a0 * 32 + 32 + l31) * HD + kk * 16 + hf * 8);
#pragma unroll
    for (int e = 0; e < 8; ++e) {
      qf0[kk][e] = (bf16)((float)qf0[kk][e] * SCALE);
      qf1[kk][e] = (bf16)((float)qf1[kk][e] * SCALE);
    }
  }
  o00 = (floatx16){}; o01 = (floatx16){};
  o10 = (floatx16){}; o11 = (floatx16){};
  l0 = 0.f; l1 = 0.f;

  for (; m < NA; m += 4)
    ASTEP2(m, a0, qf0, qf1);

  l0 += __shfl_xor(l0, 32, 64);
  l1 += __shfl_xor(l1, 32, 64);

  COMBINE(o00, o01, l0, a0 * 32);
  __syncthreads();
  COMBINE(o10, o11, l1, a0 * 32 + 32);
  __syncthreads();

  // ================= B group: tiles b0, b0+1 =================
#pragma unroll
  for (int kk = 0; kk < 4; ++kk) {
    qf0[kk] = *(const bf16x8*)(Qb + (size_t)(b0 * 32 + l31) * HD + kk * 16 + hf * 8);
    qf1[kk] = *(const bf16x8*)(Qb + (size_t)(b0 * 32 + 32 + l31) * HD + kk * 16 + hf * 8);
#pragma unroll
    for (int e = 0; e < 8; ++e) {
      qf0[kk][e] = (bf16)((float)qf0[kk][e] * SCALE);
      qf1[kk][e] = (bf16)((float)qf1[kk][e] * SCALE);
    }
  }
  o00 = (floatx16){}; o01 = (floatx16){};
  o10 = (floatx16){}; o11 = (floatx16){};
  l0 = 0.f; l1 = 0.f;

  for (; m < 66; m += 4)
    ASTEP2(m - NA, b0, qf0, qf1);

  l0 += __shfl_xor(l0, 32, 64);
  l1 += __shfl_xor(l1, 32, 64);

  COMBINE(o00, o01, l0, b0 * 32);
  __syncthreads();
  COMBINE(o10, o11, l1, b0 * 32 + 32);
}

// ---------------------------------------------------------------------------
// Attention v4 (row-major K/V) — kept as fallback for small workspaces.
// ---------------------------------------------------------------------------
#define PSTR 40

__global__ __launch_bounds__(256) void attn_v4(
    const bf16* __restrict__ qkv, float* __restrict__ out) {
  const bf16* Q = qkv;
  const bf16* K = qkv + (size_t)BATCH * T_SEQ * HDIM;
  const bf16* V = K + (size_t)BATCH * T_SEQ * HDIM;

  __shared__ __align__(16) bf16 pl[4 * 16 * PSTR];

  const int lane = threadIdx.x & 63;
  const int w    = threadIdx.x >> 6;
  const int l15  = lane & 15;
  const int quad = lane >> 4;

  const int bh = blockIdx.x;
  const int j  = blockIdx.y;
  const bf16* Qb = Q + (size_t)bh * T_SEQ * HD;
  const bf16* Kb = K + (size_t)bh * T_SEQ * HD;
  const bf16* Vb = V + (size_t)bh * T_SEQ * HD;
  const int b = bh >> 4, h = bh & (NH - 1);

  const int qt = (w == 0) ? j : (w == 1) ? (63 - j) : (w == 2) ? (64 + j) : (127 - j);
  const int q0 = qt * 16;

  bf16* pw = pl + w * 16 * PSTR;

  bf16x8 qf0 = *(const bf16x8*)(Qb + (size_t)(q0 + l15) * HD + quad * 8);
  bf16x8 qf1 = *(const bf16x8*)(Qb + (size_t)(q0 + l15) * HD + 32 + quad * 8);
  for (int e = 0; e < 8; ++e) {
    qf0[e] = (bf16)((float)qf0[e] * SCALE);
    qf1[e] = (bf16)((float)qf1[e] * SCALE);
  }

  floatx4 o[4] = {};
  float lacc[4] = {0.f, 0.f, 0.f, 0.f};

  const int S = (qt >> 1) + 1;

  for (int s0 = 0; s0 < S; ++s0) {
    const int kv = s0 * 32;

    bf16 ve[4][8];
    for (int jjj = 0; jjj < 8; ++jjj) {
      const bf16* vrow = Vb + (size_t)(kv + quad * 8 + jjj) * HD + l15;
      for (int dt = 0; dt < 4; ++dt) ve[dt][jjj] = vrow[dt * 16];
    }

    floatx4 sa[2];
    for (int nt = 0; nt < 2; ++nt) {
      const int kbase = kv + nt * 16;
      bf16x8 k0 = *(const bf16x8*)(Kb + (size_t)(kbase + l15) * HD + quad * 8);
      bf16x8 k1 = *(const bf16x8*)(Kb + (size_t)(kbase + l15) * HD + 32 + quad * 8);
      floatx4 s = {};
      s = mfma16(qf0, k0, s);
      s = mfma16(qf1, k1, s);
      sa[nt] = s;
    }

    float p[2][4];
    for (int nt = 0; nt < 2; ++nt)
      for (int r = 0; r < 4; ++r) p[nt][r] = __expf(sa[nt][r]);
    if (s0 == S - 1) {
      for (int nt = 0; nt < 2; ++nt) {
        const int kg = kv + nt * 16 + l15;
        for (int r = 0; r < 4; ++r) {
          const int qg = q0 + quad * 4 + r;
          if (kg > qg) p[nt][r] = 0.f;
        }
      }
    }
    for (int r = 0; r < 4; ++r) lacc[r] += p[0][r] + p[1][r];

    for (int nt = 0; nt < 2; ++nt)
      for (int r = 0; r < 4; ++r)
        pw[(quad * 4 + r) * PSTR + nt * 16 + l15] = (bf16)p[nt][r];
    __asm__ __volatile__("s_waitcnt lgkmcnt(0)" ::: "memory");
    const bf16x8 pf = *(const bf16x8*)(pw + l15 * PSTR + quad * 8);

    for (int dt = 0; dt < 4; ++dt) {
      bf16x8 vf;
      for (int jjj = 0; jjj < 8; ++jjj) vf[jjj] = ve[dt][jjj];
      o[dt] = mfma16(pf, vf, o[dt]);
    }
  }

  for (int r = 0; r < 4; ++r) {
    float v = lacc[r];
    for (int off = 1; off < 16; off <<= 1) v += __shfl_xor(v, off, 64);
    lacc[r] = v;
  }

  for (int dt = 0; dt < 4; ++dt) {
    for (int r = 0; r < 4; ++r) {
      const int t = q0 + quad * 4 + r;
      out[((size_t)(b * T_SEQ + t) * HDIM) + h * HD + dt * 16 + l15] =
          o[dt][r] / lacc[r];
    }
  }
}

// ---------------------------------------------------------------------------
extern "C" void kernel_launch(void* const* d_in, const int* in_sizes, int n_in,
                              void* d_out, int out_size, void* d_ws, size_t ws_size,
                              hipStream_t stream) {
  const float* x  = (const float*)d_in[0];
  const float* Wq = (const float*)d_in[1];
  const float* bq = (const float*)d_in[2];
  const float* Wk = (const float*)d_in[3];
  const float* bk = (const float*)d_in[4];
  const float* Wv = (const float*)d_in[5];
  const float* bv = (const float*)d_in[6];
  float* out = (float*)d_out;

  const size_t elems = (size_t)BATCH * T_SEQ * HDIM;   // 4M
  bf16* qkv  = (bf16*)d_ws;                            // 24 MB (Q | Kpack | Vpack)
  bf16* xbuf = qkv + 3 * elems;                        // +8 MB (x bf16)
  bf16* wbuf = xbuf + elems;                           // +6 MB (W bf16)

  const bool fast = ws_size >= (size_t)39 * 1024 * 1024;
  dim3 g1(BATCH * T_SEQ / 128, 3 * HDIM / 128);
  if (fast) {
    cvt_f32_bf16<<<dim3(2048), 256, 0, stream>>>(x, Wq, Wk, Wv, xbuf, wbuf);
    qkv_gemm_lds<<<g1, 256, 0, stream>>>(xbuf, wbuf, bq, bk, bv, qkv);
    attn_v15<<<dim3(32, 16), 256, 0, stream>>>(qkv, out);
  } else {
    qkv_gemm_f32<<<g1, 256, 0, stream>>>(x, Wq, bq, Wk, bk, Wv, bv, qkv);
    attn_v4<<<dim3(BATCH * NH, 32), 256, 0, stream>>>(qkv, out);
  }
}

// Round 17
// 148.085 us; speedup vs baseline: 1.0378x; 1.0021x over previous
//
#include <hip/hip_runtime.h>
#include <math.h>

typedef __bf16 bf16;
typedef __bf16 bf16x8 __attribute__((ext_vector_type(8)));
typedef __bf16 bf16x4 __attribute__((ext_vector_type(4)));
typedef __bf16 bf16x2 __attribute__((ext_vector_type(2)));
typedef float floatx4 __attribute__((ext_vector_type(4)));
typedef float floatx16 __attribute__((ext_vector_type(16)));
typedef unsigned int uintx4 __attribute__((ext_vector_type(4)));

#define T_SEQ 2048
#define NH 16
#define HD 64
#define HDIM 1024
#define BATCH 2
#define SCALE 0.03125f  // 1/sqrt(1024) per reference

static __device__ __forceinline__ floatx4 mfma16(bf16x8 a, bf16x8 b, floatx4 c) {
  return __builtin_amdgcn_mfma_f32_16x16x32_bf16(a, b, c, 0, 0, 0);
}
static __device__ __forceinline__ floatx16 mfma32(bf16x8 a, bf16x8 b, floatx16 c) {
  return __builtin_amdgcn_mfma_f32_32x32x16_bf16(a, b, c, 0, 0, 0);
}

static __device__ __forceinline__ unsigned int packbf(float a, float b) {
  bf16x2 t; t[0] = (bf16)a; t[1] = (bf16)b;
  return __builtin_bit_cast(unsigned int, t);
}

static __device__ __forceinline__ bf16x8 cvt_pack(floatx4 lo, floatx4 hi) {
  bf16x8 r;
  r[0] = (bf16)lo[0]; r[1] = (bf16)lo[1]; r[2] = (bf16)lo[2]; r[3] = (bf16)lo[3];
  r[4] = (bf16)hi[0]; r[5] = (bf16)hi[1]; r[6] = (bf16)hi[2]; r[7] = (bf16)hi[3];
  return r;
}

typedef const __attribute__((address_space(1))) void* gas_ptr;
typedef __attribute__((address_space(3))) void* las_ptr;
static __device__ __forceinline__ void load_lds16(const bf16* g, bf16* l) {
  __builtin_amdgcn_global_load_lds((gas_ptr)g, (las_ptr)l, 16, 0, 0);
}

// ---------------------------------------------------------------------------
// cvt v2: grid-stride, 2048 blocks.
// ---------------------------------------------------------------------------
__global__ __launch_bounds__(256) void cvt_f32_bf16(
    const float* __restrict__ x, const float* __restrict__ Wq,
    const float* __restrict__ Wk, const float* __restrict__ Wv,
    bf16* __restrict__ xb, bf16* __restrict__ wb) {
  const size_t XN = (size_t)BATCH * T_SEQ * HDIM;   // 4M
  const size_t WN = (size_t)HDIM * HDIM;            // 1M
  const size_t TOT4 = (XN + 3 * WN) / 4;            // 1.75M chunks of 4
  const size_t stride = (size_t)gridDim.x * 256;

  for (size_t c = blockIdx.x * 256 + threadIdx.x; c < TOT4; c += stride) {
    const size_t i4 = c * 4;
    const float* src; bf16* dst; size_t off;
    if (i4 < XN)                { src = x;  dst = xb;           off = i4; }
    else if (i4 < XN + WN)      { src = Wq; dst = wb;           off = i4 - XN; }
    else if (i4 < XN + 2 * WN)  { src = Wk; dst = wb + WN;      off = i4 - XN - WN; }
    else                        { src = Wv; dst = wb + 2 * WN;  off = i4 - XN - 2 * WN; }
    floatx4 v = *(const floatx4*)(src + off);
    bf16x4 o; o[0]=(bf16)v[0]; o[1]=(bf16)v[1]; o[2]=(bf16)v[2]; o[3]=(bf16)v[3];
    *(bf16x4*)(dst + off) = o;
  }
}

// ---------------------------------------------------------------------------
// QKV GEMM v5 (R13/R16-verified best): BK=32 double-buffer pipeline +
// LDS-staged vector epilogue with PACKED K/V layout.  grid (32, 24) x 256.
// ---------------------------------------------------------------------------
__global__ __launch_bounds__(256) void qkv_gemm_lds(
    const bf16* __restrict__ xb, const bf16* __restrict__ wb,
    const float* __restrict__ bq, const float* __restrict__ bk,
    const float* __restrict__ bv, bf16* __restrict__ qkv) {
  __shared__ __align__(16) bf16 smem[16384];   // 32 KB

  const int m0  = blockIdx.x * 128;
  const int n0g = blockIdx.y * 128;
  const int z   = n0g >> 10;
  const float* bias = (z == 0) ? bq : (z == 1) ? bk : bv;
  bf16* out = qkv + (size_t)z * BATCH * T_SEQ * HDIM;

  const int lane = threadIdx.x & 63;
  const int w    = threadIdx.x >> 6;
  const int l15  = lane & 15;
  const int quad = lane >> 4;
  const int wm = w & 1, wn = w >> 1;

  const int srow = w * 32 + (lane >> 2);
  const int scol = (lane & 3) * 8;
  const bf16* aG0 = xb + (size_t)(m0 + srow) * HDIM + scol;
  const bf16* aG1 = xb + (size_t)(m0 + srow + 16) * HDIM + scol;
  const bf16* bG0 = wb + (size_t)(n0g + srow) * HDIM + scol;
  const bf16* bG1 = wb + (size_t)(n0g + srow + 16) * HDIM + scol;

#define GSTAGE(BUF, KOFF)                                                    \
  {                                                                          \
    bf16* aB = smem + (BUF) * 4096;                                          \
    bf16* bB = smem + 8192 + (BUF) * 4096;                                   \
    load_lds16(aG0 + (KOFF), aB + (w * 32) * 32);                            \
    load_lds16(aG1 + (KOFF), aB + (w * 32 + 16) * 32);                       \
    load_lds16(bG0 + (KOFF), bB + (w * 32) * 32);                            \
    load_lds16(bG1 + (KOFF), bB + (w * 32 + 16) * 32);                       \
  }

  floatx4 acc[4][4] = {};

  GSTAGE(0, 0);
  __syncthreads();

  for (int k0 = 0; k0 < 32; ++k0) {
    const int cur = k0 & 1;
    if (k0 < 31) GSTAGE(cur ^ 1, (k0 + 1) * 32);

    const bf16* A = smem + cur * 4096;
    const bf16* B = smem + 8192 + cur * 4096;

    bf16x8 af[4], bf[4];
#pragma unroll
    for (int i = 0; i < 4; ++i)
      af[i] = *(const bf16x8*)(A + (wm * 64 + i * 16 + l15) * 32 + quad * 8);
#pragma unroll
    for (int jj = 0; jj < 4; ++jj)
      bf[jj] = *(const bf16x8*)(B + (wn * 64 + jj * 16 + l15) * 32 + quad * 8);
#pragma unroll
    for (int i = 0; i < 4; ++i)
#pragma unroll
      for (int jj = 0; jj < 4; ++jj)
        acc[i][jj] = mfma16(af[i], bf[jj], acc[i][jj]);

    __syncthreads();
  }
#undef GSTAGE

  // ---- epilogue: stage wave's 64x64 tile in LDS as the final memory image ----
  const size_t bhS = (size_t)T_SEQ * HD;
  bf16* pwv = smem + w * 4096;                       // 8KB per-wave buffer
  const int gm0 = m0 + wm * 64;
  const int t0w = gm0 & (T_SEQ - 1);
  const int bbw = gm0 >> 11;
  const int nl0 = (n0g + wn * 64) & (HDIM - 1);
  const int hw  = nl0 >> 6;
  bf16* obh = out + (size_t)(bbw * NH + hw) * bhS;

#pragma unroll
  for (int jj = 0; jj < 4; ++jj) {
    const int dl = jj * 16 + l15;                    // d_local 0..63
    const float bvv = bias[nl0 + dl];
#pragma unroll
    for (int i = 0; i < 4; ++i) {
#pragma unroll
      for (int r = 0; r < 4; ++r) {
        const int tl = i * 16 + quad * 4 + r;        // t_local 0..63
        const bf16 val = (bf16)(acc[i][jj][r] + bvv);
        int off;
        if (z == 0) {
          off = tl * 64 + dl;                        // Q row-major
        } else if (z == 1) {                         // K packed
          off = ((tl >> 5) << 11) + ((dl >> 4) << 9) +
                (((tl & 31) + (((dl >> 3) & 1) << 5)) << 3) + (dl & 7);
        } else {                                     // V packed (+T)
          off = ((tl >> 5) << 11) +
                ((((tl >> 4) & 1) + (((dl >> 5) & 1) << 1)) << 9) +
                (((dl & 31) + (((tl >> 3) & 1) << 5)) << 3) + (tl & 7);
        }
        pwv[off] = val;
      }
    }
  }
  __asm__ __volatile__("s_waitcnt lgkmcnt(0)" ::: "memory");

  const size_t gbase = (z == 0) ? (size_t)t0w * 64 : (size_t)(t0w >> 5) * 2048;
#pragma unroll
  for (int c = 0; c < 8; ++c)
    *(bf16x8*)(obh + gbase + c * 512 + lane * 8) =
        *(const bf16x8*)(pwv + c * 512 + lane * 8);
}

// ---------------------------------------------------------------------------
// Fallback QKV GEMM (fp32 staging, row-major output) for small workspaces.
// ---------------------------------------------------------------------------
#define LSTR 40

__global__ __launch_bounds__(256) void qkv_gemm_f32(
    const float* __restrict__ x,
    const float* __restrict__ Wq, const float* __restrict__ bq,
    const float* __restrict__ Wk, const float* __restrict__ bk,
    const float* __restrict__ Wv, const float* __restrict__ bv,
    bf16* __restrict__ qkv) {
  __shared__ __align__(16) bf16 As[128 * LSTR];
  __shared__ __align__(16) bf16 Bs[128 * LSTR];

  const int n0g = blockIdx.y * 128;
  const int z   = n0g >> 10;
  const int n0  = n0g & (HDIM - 1);
  const float* W    = (z == 0) ? Wq : (z == 1) ? Wk : Wv;
  const float* bias = (z == 0) ? bq : (z == 1) ? bk : bv;
  bf16* out = qkv + (size_t)z * BATCH * T_SEQ * HDIM;
  const int m0 = blockIdx.x * 128;

  const int lane = threadIdx.x & 63;
  const int w    = threadIdx.x >> 6;
  const int l15  = lane & 15;
  const int quad = lane >> 4;
  const int wm = w & 1, wn = w >> 1;

  const int srow  = threadIdx.x >> 1;
  const int shalf = threadIdx.x & 1;
  const float* aSrc = x + (size_t)(m0 + srow) * HDIM + shalf * 16;
  const float* bSrc = W + (size_t)(n0 + srow) * HDIM + shalf * 16;
  bf16* aDst = As + srow * LSTR + shalf * 16;
  bf16* bDst = Bs + srow * LSTR + shalf * 16;

  floatx4 acc[4][4] = {};

  for (int k0 = 0; k0 < HDIM; k0 += 32) {
    floatx4 a0 = *(const floatx4*)(aSrc + k0);
    floatx4 a1 = *(const floatx4*)(aSrc + k0 + 4);
    floatx4 a2 = *(const floatx4*)(aSrc + k0 + 8);
    floatx4 a3 = *(const floatx4*)(aSrc + k0 + 12);
    floatx4 b0 = *(const floatx4*)(bSrc + k0);
    floatx4 b1 = *(const floatx4*)(bSrc + k0 + 4);
    floatx4 b2 = *(const floatx4*)(bSrc + k0 + 8);
    floatx4 b3 = *(const floatx4*)(bSrc + k0 + 12);

    __syncthreads();
    *(bf16x8*)(aDst)     = cvt_pack(a0, a1);
    *(bf16x8*)(aDst + 8) = cvt_pack(a2, a3);
    *(bf16x8*)(bDst)     = cvt_pack(b0, b1);
    *(bf16x8*)(bDst + 8) = cvt_pack(b2, b3);
    __syncthreads();

    bf16x8 af[4], bff[4];
    for (int i = 0; i < 4; ++i)
      af[i] = *(const bf16x8*)(As + (wm * 64 + i * 16 + l15) * LSTR + quad * 8);
    for (int jj = 0; jj < 4; ++jj)
      bff[jj] = *(const bf16x8*)(Bs + (wn * 64 + jj * 16 + l15) * LSTR + quad * 8);
    for (int i = 0; i < 4; ++i)
      for (int jj = 0; jj < 4; ++jj)
        acc[i][jj] = mfma16(af[i], bff[jj], acc[i][jj]);
  }

  for (int jj = 0; jj < 4; ++jj) {
    const int nloc = n0 + wn * 64 + jj * 16 + l15;
    const float bvv = bias[nloc];
    const int h = nloc >> 6, d = nloc & (HD - 1);
    for (int i = 0; i < 4; ++i) {
      for (int r = 0; r < 4; ++r) {
        const int gm = m0 + wm * 64 + i * 16 + quad * 4 + r;
        const int bb = gm >> 11, t = gm & (T_SEQ - 1);
        out[((size_t)((bb * NH + h) * T_SEQ) + t) * HD + d] = (bf16)(acc[i][jj][r] + bvv);
      }
    }
  }
}

// ---------------------------------------------------------------------------
// Attention v18 = v15 + ONE-WINDOW REGISTER PREFETCH.
// v15 exposed the full K/V load latency per window (loads consumed by the
// first QK MFMA immediately after issue, 2 waves/SIMD of overlap).  v18
// issues window m+4's 8 fragment loads into shadow regs BEFORE computing
// window m's two TBODYs (~600 cy of cover), rotating registers after.
// Everything else identical to v15.  grid (32, 16) x 256; 2 blocks/CU.
// ---------------------------------------------------------------------------
#define LOADW(G, KF, VF)                                                       \
  {                                                                            \
    const bf16* kp_ = Kb + (G) * 2048 + lane * 8;                              \
    KF[0] = *(const bf16x8*)(kp_);                                             \
    KF[1] = *(const bf16x8*)(kp_ + 512);                                       \
    KF[2] = *(const bf16x8*)(kp_ + 1024);                                      \
    KF[3] = *(const bf16x8*)(kp_ + 1536);                                      \
    const bf16* vp_ = Vb + (G) * 2048 + lane * 8;                              \
    VF[0] = *(const bf16x8*)(vp_);                                             \
    VF[1] = *(const bf16x8*)(vp_ + 512);                                       \
    VF[2] = *(const bf16x8*)(vp_ + 1024);                                      \
    VF[3] = *(const bf16x8*)(vp_ + 1536);                                      \
  }

#define TBODY(QF, DIAG, O0, O1, LL)                                            \
  {                                                                            \
    floatx16 s = {};                                                           \
    s = mfma32(cKF[0], QF[0], s);                                              \
    s = mfma32(cKF[1], QF[1], s);                                              \
    s = mfma32(cKF[2], QF[2], s);                                              \
    s = mfma32(cKF[3], QF[3], s);                                              \
    float pp[16];                                                              \
    _Pragma("unroll")                                                          \
    for (int r = 0; r < 16; ++r) pp[r] = __expf(s[r]);                         \
    if (DIAG) {                                                                \
      _Pragma("unroll")                                                        \
      for (int r = 0; r < 16; ++r) {                                           \
        const int krow = (r & 3) + 8 * (r >> 2) + 4 * hf;                      \
        if (krow > l31) pp[r] = 0.f;                                           \
      }                                                                        \
    }                                                                          \
    float psum = 0.f;                                                          \
    _Pragma("unroll")                                                          \
    for (int r = 0; r < 16; ++r) psum += pp[r];                                \
    LL += psum;                                                                \
    unsigned int Dg[4][2], Xg[4][2];                                           \
    _Pragma("unroll")                                                          \
    for (int a = 0; a < 4; ++a) {                                              \
      Dg[a][0] = packbf(pp[4 * a + 0], pp[4 * a + 1]);                         \
      Dg[a][1] = packbf(pp[4 * a + 2], pp[4 * a + 3]);                         \
    }                                                                          \
    _Pragma("unroll")                                                          \
    for (int a = 0; a < 4; ++a) {                                              \
      Xg[a][0] = (unsigned int)__shfl_xor((int)Dg[a][0], 32, 64);              \
      Xg[a][1] = (unsigned int)__shfl_xor((int)Dg[a][1], 32, 64);              \
    }                                                                          \
    uintx4 f0u, f1u;                                                           \
    f0u[0] = hf ? Xg[1][0] : Dg[0][0];                                         \
    f0u[1] = hf ? Xg[1][1] : Dg[0][1];                                         \
    f0u[2] = hf ? Dg[1][0] : Xg[0][0];                                         \
    f0u[3] = hf ? Dg[1][1] : Xg[0][1];                                         \
    f1u[0] = hf ? Xg[3][0] : Dg[2][0];                                         \
    f1u[1] = hf ? Xg[3][1] : Dg[2][1];                                         \
    f1u[2] = hf ? Dg[3][0] : Xg[2][0];                                         \
    f1u[3] = hf ? Dg[3][1] : Xg[2][1];                                         \
    bf16x8 pf0 = __builtin_bit_cast(bf16x8, f0u);                              \
    bf16x8 pf1 = __builtin_bit_cast(bf16x8, f1u);                              \
    O0 = mfma32(cVF[0], pf0, O0);                                              \
    O0 = mfma32(cVF[1], pf1, O0);                                              \
    O1 = mfma32(cVF[2], pf0, O1);                                              \
    O1 = mfma32(cVF[3], pf1, O1);                                              \
  }

// combine one tile's partials across 4 waves; vectorized coalesced stores
#define COMBINE(O0, O1, LL, QBASE)                                             \
  {                                                                            \
    _Pragma("unroll")                                                          \
    for (int r = 0; r < 16; ++r) {                                             \
      ps[w][lane][r]      = O0[r];                                             \
      ps[w][lane][16 + r] = O1[r];                                             \
    }                                                                          \
    ps[w][lane][32] = LL;                                                      \
    __syncthreads();                                                           \
    const int ql = threadIdx.x >> 3;                                           \
    const int ch = threadIdx.x & 7;                                            \
    const float ls = ps[0][ql][32] + ps[1][ql][32] +                           \
                     ps[2][ql][32] + ps[3][ql][32];                            \
    const float inv = 1.f / ls;                                                \
    float ov[8];                                                               \
    _Pragma("unroll")                                                          \
    for (int e = 0; e < 8; ++e) {                                              \
      const int d  = ch * 8 + e;                                               \
      const int dp = d & 31;                                                   \
      const int lsrc = ql + (((dp >> 2) & 1) << 5);                            \
      const int rr = (dp & 3) + ((dp >> 3) << 2) + ((d >> 5) << 4);            \
      ov[e] = (ps[0][lsrc][rr] + ps[1][lsrc][rr] +                             \
               ps[2][lsrc][rr] + ps[3][lsrc][rr]) * inv;                       \
    }                                                                          \
    float* ob = out + ((size_t)(b * T_SEQ + (QBASE) + ql)) * HDIM +            \
                hh * HD + ch * 8;                                              \
    floatx4 v0_ = {ov[0], ov[1], ov[2], ov[3]};                                \
    floatx4 v1_ = {ov[4], ov[5], ov[6], ov[7]};                                \
    *(floatx4*)(ob)     = v0_;                                                 \
    *(floatx4*)(ob + 4) = v1_;                                                 \
  }

__global__ __launch_bounds__(256, 2) void attn_v18(
    const bf16* __restrict__ qkv, float* __restrict__ out) {
  __shared__ float ps[4][64][33];   // 33792 B partial-combine buffer

  const int lane = threadIdx.x & 63;
  const int w    = threadIdx.x >> 6;
  const int l31  = lane & 31;
  const int hf   = lane >> 5;

  // XCD-locality remap (bijective over 512 blocks)
  const int lin = blockIdx.x + (blockIdx.y << 5);
  const int bh  = ((lin & 7) << 2) + ((lin >> 3) & 3);
  const int p   = lin >> 5;             // 0..15

  const int a0 = 2 * p;                 // A tiles {a0, a0+1}
  const int b0 = 62 - 2 * p;            // B tiles {b0, b0+1}
  const int NA = 2 * p + 2;             // A windows; NA + NB == 66

  const bf16* Qb = qkv + (size_t)bh * T_SEQ * HD;
  const bf16* Kb = qkv + (size_t)BATCH * T_SEQ * HDIM + (size_t)bh * T_SEQ * HD;
  const bf16* Vb = qkv + (size_t)2 * BATCH * T_SEQ * HDIM + (size_t)bh * T_SEQ * HD;
  const int b = bh >> 4, hh = bh & (NH - 1);

  bf16x8 qf0[4], qf1[4];
  bf16x8 cKF[4], cVF[4], nKF[4], nVF[4];
  floatx16 o00, o01, o10, o11;
  float l0, l1;
  int m = w;

  // ================= A group: tiles a0, a0+1 =================
#pragma unroll
  for (int kk = 0; kk < 4; ++kk) {
    qf0[kk] = *(const bf16x8*)(Qb + (size_t)(a0 * 32 + l31) * HD + kk * 16 + hf * 8);
    qf1[kk] = *(const bf16x8*)(Qb + (size_t)(a0 * 32 + 32 + l31) * HD + kk * 16 + hf * 8);
#pragma unroll
    for (int e = 0; e < 8; ++e) {
      qf0[kk][e] = (bf16)((float)qf0[kk][e] * SCALE);
      qf1[kk][e] = (bf16)((float)qf1[kk][e] * SCALE);
    }
  }
  o00 = (floatx16){}; o01 = (floatx16){};
  o10 = (floatx16){}; o11 = (floatx16){};
  l0 = 0.f; l1 = 0.f;

  if (m < NA) LOADW(m, cKF, cVF);
  for (; m < NA; m += 4) {
    const bool more = (m + 4 < NA);
    if (more) LOADW(m + 4, nKF, nVF);   // prefetch: lands under the 2 TBODYs
    {
      const int g_ = m;
      if (g_ <= a0) TBODY(qf0, g_ == a0, o00, o01, l0);
      TBODY(qf1, g_ == a0 + 1, o10, o11, l1);
    }
    if (more) {
#pragma unroll
      for (int q = 0; q < 4; ++q) { cKF[q] = nKF[q]; cVF[q] = nVF[q]; }
    }
  }

  l0 += __shfl_xor(l0, 32, 64);
  l1 += __shfl_xor(l1, 32, 64);

  COMBINE(o00, o01, l0, a0 * 32);
  __syncthreads();
  COMBINE(o10, o11, l1, a0 * 32 + 32);
  __syncthreads();

  // ================= B group: tiles b0, b0+1 =================
#pragma unroll
  for (int kk = 0; kk < 4; ++kk) {
    qf0[kk] = *(const bf16x8*)(Qb + (size_t)(b0 * 32 + l31) * HD + kk * 16 + hf * 8);
    qf1[kk] = *(const bf16x8*)(Qb + (size_t)(b0 * 32 + 32 + l31) * HD + kk * 16 + hf * 8);
#pragma unroll
    for (int e = 0; e < 8; ++e) {
      qf0[kk][e] = (bf16)((float)qf0[kk][e] * SCALE);
      qf1[kk][e] = (bf16)((float)qf1[kk][e] * SCALE);
    }
  }
  o00 = (floatx16){}; o01 = (floatx16){};
  o10 = (floatx16){}; o11 = (floatx16){};
  l0 = 0.f; l1 = 0.f;

  if (m < 66) LOADW(m - NA, cKF, cVF);
  for (; m < 66; m += 4) {
    const bool more = (m + 4 < 66);
    if (more) LOADW(m + 4 - NA, nKF, nVF);
    {
      const int g_ = m - NA;
      if (g_ <= b0) TBODY(qf0, g_ == b0, o00, o01, l0);
      TBODY(qf1, g_ == b0 + 1, o10, o11, l1);
    }
    if (more) {
#pragma unroll
      for (int q = 0; q < 4; ++q) { cKF[q] = nKF[q]; cVF[q] = nVF[q]; }
    }
  }

  l0 += __shfl_xor(l0, 32, 64);
  l1 += __shfl_xor(l1, 32, 64);

  COMBINE(o00, o01, l0, b0 * 32);
  __syncthreads();
  COMBINE(o10, o11, l1, b0 * 32 + 32);
}

// ---------------------------------------------------------------------------
// Attention v4 (row-major K/V) — kept as fallback for small workspaces.
// ---------------------------------------------------------------------------
#define PSTR 40

__global__ __launch_bounds__(256) void attn_v4(
    const bf16* __restrict__ qkv, float* __restrict__ out) {
  const bf16* Q = qkv;
  const bf16* K = qkv + (size_t)BATCH * T_SEQ * HDIM;
  const bf16* V = K + (size_t)BATCH * T_SEQ * HDIM;

  __shared__ __align__(16) bf16 pl[4 * 16 * PSTR];

  const int lane = threadIdx.x & 63;
  const int w    = threadIdx.x >> 6;
  const int l15  = lane & 15;
  const int quad = lane >> 4;

  const int bh = blockIdx.x;
  const int j  = blockIdx.y;
  const bf16* Qb = Q + (size_t)bh * T_SEQ * HD;
  const bf16* Kb = K + (size_t)bh * T_SEQ * HD;
  const bf16* Vb = V + (size_t)bh * T_SEQ * HD;
  const int b = bh >> 4, h = bh & (NH - 1);

  const int qt = (w == 0) ? j : (w == 1) ? (63 - j) : (w == 2) ? (64 + j) : (127 - j);
  const int q0 = qt * 16;

  bf16* pw = pl + w * 16 * PSTR;

  bf16x8 qf0 = *(const bf16x8*)(Qb + (size_t)(q0 + l15) * HD + quad * 8);
  bf16x8 qf1 = *(const bf16x8*)(Qb + (size_t)(q0 + l15) * HD + 32 + quad * 8);
  for (int e = 0; e < 8; ++e) {
    qf0[e] = (bf16)((float)qf0[e] * SCALE);
    qf1[e] = (bf16)((float)qf1[e] * SCALE);
  }

  floatx4 o[4] = {};
  float lacc[4] = {0.f, 0.f, 0.f, 0.f};

  const int S = (qt >> 1) + 1;

  for (int s0 = 0; s0 < S; ++s0) {
    const int kv = s0 * 32;

    bf16 ve[4][8];
    for (int jjj = 0; jjj < 8; ++jjj) {
      const bf16* vrow = Vb + (size_t)(kv + quad * 8 + jjj) * HD + l15;
      for (int dt = 0; dt < 4; ++dt) ve[dt][jjj] = vrow[dt * 16];
    }

    floatx4 sa[2];
    for (int nt = 0; nt < 2; ++nt) {
      const int kbase = kv + nt * 16;
      bf16x8 k0 = *(const bf16x8*)(Kb + (size_t)(kbase + l15) * HD + quad * 8);
      bf16x8 k1 = *(const bf16x8*)(Kb + (size_t)(kbase + l15) * HD + 32 + quad * 8);
      floatx4 s = {};
      s = mfma16(qf0, k0, s);
      s = mfma16(qf1, k1, s);
      sa[nt] = s;
    }

    float p[2][4];
    for (int nt = 0; nt < 2; ++nt)
      for (int r = 0; r < 4; ++r) p[nt][r] = __expf(sa[nt][r]);
    if (s0 == S - 1) {
      for (int nt = 0; nt < 2; ++nt) {
        const int kg = kv + nt * 16 + l15;
        for (int r = 0; r < 4; ++r) {
          const int qg = q0 + quad * 4 + r;
          if (kg > qg) p[nt][r] = 0.f;
        }
      }
    }
    for (int r = 0; r < 4; ++r) lacc[r] += p[0][r] + p[1][r];

    for (int nt = 0; nt < 2; ++nt)
      for (int r = 0; r < 4; ++r)
        pw[(quad * 4 + r) * PSTR + nt * 16 + l15] = (bf16)p[nt][r];
    __asm__ __volatile__("s_waitcnt lgkmcnt(0)" ::: "memory");
    const bf16x8 pf = *(const bf16x8*)(pw + l15 * PSTR + quad * 8);

    for (int dt = 0; dt < 4; ++dt) {
      bf16x8 vf;
      for (int jjj = 0; jjj < 8; ++jjj) vf[jjj] = ve[dt][jjj];
      o[dt] = mfma16(pf, vf, o[dt]);
    }
  }

  for (int r = 0; r < 4; ++r) {
    float v = lacc[r];
    for (int off = 1; off < 16; off <<= 1) v += __shfl_xor(v, off, 64);
    lacc[r] = v;
  }

  for (int dt = 0; dt < 4; ++dt) {
    for (int r = 0; r < 4; ++r) {
      const int t = q0 + quad * 4 + r;
      out[((size_t)(b * T_SEQ + t) * HDIM) + h * HD + dt * 16 + l15] =
          o[dt][r] / lacc[r];
    }
  }
}

// ---------------------------------------------------------------------------
extern "C" void kernel_launch(void* const* d_in, const int* in_sizes, int n_in,
                              void* d_out, int out_size, void* d_ws, size_t ws_size,
                              hipStream_t stream) {
  const float* x  = (const float*)d_in[0];
  const float* Wq = (const float*)d_in[1];
  const float* bq = (const float*)d_in[2];
  const float* Wk = (const float*)d_in[3];
  const float* bk = (const float*)d_in[4];
  const float* Wv = (const float*)d_in[5];
  const float* bv = (const float*)d_in[6];
  float* out = (float*)d_out;

  const size_t elems = (size_t)BATCH * T_SEQ * HDIM;   // 4M
  bf16* qkv  = (bf16*)d_ws;                            // 24 MB (Q | Kpack | Vpack)
  bf16* xbuf = qkv + 3 * elems;                        // +8 MB (x bf16)
  bf16* wbuf = xbuf + elems;                           // +6 MB (W bf16)

  const bool fast = ws_size >= (size_t)39 * 1024 * 1024;
  dim3 g1(BATCH * T_SEQ / 128, 3 * HDIM / 128);
  if (fast) {
    cvt_f32_bf16<<<dim3(2048), 256, 0, stream>>>(x, Wq, Wk, Wv, xbuf, wbuf);
    qkv_gemm_lds<<<g1, 256, 0, stream>>>(xbuf, wbuf, bq, bk, bv, qkv);
    attn_v18<<<dim3(32, 16), 256, 0, stream>>>(qkv, out);
  } else {
    qkv_gemm_f32<<<g1, 256, 0, stream>>>(x, Wq, bq, Wk, bk, Wv, bv, qkv);
    attn_v4<<<dim3(BATCH * NH, 32), 256, 0, stream>>>(qkv, out);
  }
}